// Round 7
// baseline (155.913 us; speedup 1.0000x reference)
//
#include <hip/hip_runtime.h>
#include <math.h>

// VectorQuantizer on MI355X — R7: 1KB-request X staging + fence-free fused tail.
// R6 falsified TLP: occupancy 2x -> time -3%. Limiter is outstanding-request
// economics of the stride-16KB dword gather (4B/lane/instr). R7 stages the
// block's X-tile (64ch x 256tok = 64KB) via global_load_dwordx4+ds_write_b128
// (1KB contiguous per wave-instr, 4x fewer requests, 4x bytes/slot), builds
// A-frags from LDS. LDS 135KB -> 1 block/CU x 8 waves (TLP proven irrelevant).
// Tail fused fence-free: counts/sse/ticket touched ONLY by device-scope
// atomics (coherence-point ops); s_waitcnt(0) before ticket bump orders them.
// No __threadfence -> no per-block L2 writeback (R3's mistake).
// Numerics identical to R4-R6: u32-key argmin, key-reconstructed SSE.
// ws: [0,2048) counts f32[512] | [2048,2056) sse f64 | [2056,2060) ticket u32

#define NTOK 131072
#define KCODES 512
#define HW 4096
#define CHW 262144
#define NELEM 8388608
#define XSTR 260  // X row stride in dwords: 16B-aligned b128 writes, cheap reads

typedef __attribute__((ext_vector_type(8))) short short8;
typedef __attribute__((ext_vector_type(4))) float f32x4;

static __device__ __forceinline__ unsigned short f2bf(float f) {
    unsigned u = __float_as_uint(f);
    unsigned r = u + 0x7FFFu + ((u >> 16) & 1u);  // RNE
    return (unsigned short)(r >> 16);
}

__global__ __launch_bounds__(512, 2) void vq_main(const float* __restrict__ in,
                                                  const float* __restrict__ w,
                                                  float* __restrict__ out,
                                                  float* __restrict__ counts,
                                                  double* __restrict__ sse_acc,
                                                  unsigned* __restrict__ ticket) {
    __shared__ unsigned short wh[KCODES * 64];     // 65536 B, frag-packed bf16 W
    __shared__ __align__(16) float xlds[64 * XSTR];  // 66560 B, X tile ch-major
    __shared__ float wsqp[KCODES];                 // 2048 B: 1.25 + ||w_k||^2
    __shared__ int idxbuf[256];                    // 1024 B
    __shared__ unsigned lastflag;

    const int tid = threadIdx.x;
    const int lane = tid & 63, wv = tid >> 6;   // wv in [0,8)
    const int col = lane & 15, quad = lane >> 4;
    const int ntok0 = blockIdx.x * 256;

    wsqp[tid] = 1.25f;
    __syncthreads();  // B1: wsqp init before ds_add

    // ---- X tile: 64 rows x 256 tokens; 1KB contiguous per wave-instr ----
    const float* xsrc = in + (ntok0 >> 12) * CHW + (ntok0 & 4095);
#pragma unroll
    for (int i = 0; i < 8; ++i) {
        const int c = i * 8 + wv;
        const float4 v = *(const float4*)(xsrc + c * HW + (lane << 2));
        *(float4*)(xlds + c * XSTR + (lane << 2)) = v;  // b128, phase-optimal
    }

    // ---- W staging (R6-identical): frag-packed bf16 + wsqp via ds_add ----
#pragma unroll
    for (int it = 0; it < 8; ++it) {
        const int g = it * 512 + tid;
        const int cc = g & 15, qd = (g >> 4) & 3, ch = (g >> 6) & 1, tt = g >> 7;
        const float4* src = (const float4*)(w + (tt * 16 + cc) * 64 + ch * 32 + qd * 8);
        const float4 v0 = src[0], v1 = src[1];
        short8 hv;
        hv[0] = (short)f2bf(v0.x); hv[1] = (short)f2bf(v0.y);
        hv[2] = (short)f2bf(v0.z); hv[3] = (short)f2bf(v0.w);
        hv[4] = (short)f2bf(v1.x); hv[5] = (short)f2bf(v1.y);
        hv[6] = (short)f2bf(v1.z); hv[7] = (short)f2bf(v1.w);
        *(short8*)(wh + g * 8) = hv;
        float ws2 = v0.x * v0.x;
        ws2 = fmaf(v0.y, v0.y, ws2); ws2 = fmaf(v0.z, v0.z, ws2);
        ws2 = fmaf(v0.w, v0.w, ws2); ws2 = fmaf(v1.x, v1.x, ws2);
        ws2 = fmaf(v1.y, v1.y, ws2); ws2 = fmaf(v1.z, v1.z, ws2);
        ws2 = fmaf(v1.w, v1.w, ws2);
        atomicAdd(&wsqp[tt * 16 + cc], ws2);
    }
    __syncthreads();  // B2: xlds + wh + wsqp complete

    // ---- A-frags from LDS (2-way/4-way reads ~ free) + xsq ----
    short8 ah[2][2];
    float xsq = 0.f;
#pragma unroll
    for (int sub = 0; sub < 2; ++sub) {
        const int t = wv * 32 + sub * 16 + col;
#pragma unroll
        for (int c = 0; c < 2; ++c)
#pragma unroll
            for (int j = 0; j < 8; ++j) {
                const float x = xlds[(c * 32 + quad * 8 + j) * XSTR + t];
                xsq = fmaf(x, x, xsq);
                ah[sub][c][j] = (short)f2bf(-2.0f * x);
            }
    }

    // ---- scan 32 tiles of 16 codes; key = (float_bits(d)<<9)|code ----
    unsigned runkey[2][4];
#pragma unroll
    for (int sub = 0; sub < 2; ++sub)
#pragma unroll
        for (int r = 0; r < 4; ++r) runkey[sub][r] = 0xFFFFFFFFu;

#pragma unroll 1
    for (int t = 0; t < 32; ++t) {
        const unsigned short* ph = wh + t * 1024 + quad * 128 + col * 8;
        const short8 b0 = *(const short8*)ph;
        const short8 b1 = *(const short8*)(ph + 512);
        const int code = t * 16 + col;
        const float seed = wsqp[code];
#pragma unroll
        for (int sub = 0; sub < 2; ++sub) {
            f32x4 acc = {seed, seed, seed, seed};
            acc = __builtin_amdgcn_mfma_f32_16x16x32_bf16(ah[sub][0], b0, acc, 0, 0, 0);
            acc = __builtin_amdgcn_mfma_f32_16x16x32_bf16(ah[sub][1], b1, acc, 0, 0, 0);
#pragma unroll
            for (int r = 0; r < 4; ++r) {
                const unsigned key = (__float_as_uint(acc[r]) << 9) | code;
                runkey[sub][r] = key < runkey[sub][r] ? key : runkey[sub][r];
            }
        }
    }

    // ---- cross-lane argmin over the 16 code-cols ----
#pragma unroll
    for (int s = 1; s < 16; s <<= 1)
#pragma unroll
        for (int sub = 0; sub < 2; ++sub)
#pragma unroll
            for (int r = 0; r < 4; ++r) {
                const unsigned o = __shfl_xor(runkey[sub][r], s, 64);
                runkey[sub][r] = o < runkey[sub][r] ? o : runkey[sub][r];
            }

    // d_best (exact from key) + publish indices
    float dsum = 0.f;
    if (col == 0) {
#pragma unroll
        for (int sub = 0; sub < 2; ++sub)
#pragma unroll
            for (int r = 0; r < 4; ++r) {
                const unsigned key = runkey[sub][r];
                idxbuf[wv * 32 + sub * 16 + quad * 4 + r] = (int)(key & 511u);
                dsum += __uint_as_float((key >> 9) | 0x3F800000u) - 1.25f;
            }
    }
    float contrib = xsq + dsum;
#pragma unroll
    for (int off = 32; off > 0; off >>= 1) contrib += __shfl_down(contrib, off, 64);
    if (lane == 0) atomicAdd(sse_acc, (double)contrib);
    __syncthreads();  // B3: idxbuf visible

    if (tid < 256) atomicAdd(&counts[idxbuf[tid]], 1.0f);

    // ---- epilogue: write w rows only (L2-hot) ----
#pragma unroll
    for (int p = 0; p < 2; ++p) {
        const int tl = p * 16 + (lane >> 2), q = lane & 3;
        const int n = ntok0 + wv * 32 + tl;
        const int bidx = idxbuf[wv * 32 + tl];
        const float4* wr = (const float4*)(w + bidx * 64 + q * 16);
        float4* op = (float4*)(out + n * 64 + q * 16);
#pragma unroll
        for (int i = 0; i < 4; ++i) op[i] = wr[i];
    }

    // ---- fence-free fused tail: atomics-only cross-block state ----
    __builtin_amdgcn_s_waitcnt(0);  // drain own vmem (incl. counts/sse atomics)
    if (tid == 0) lastflag = (atomicAdd(ticket, 1u) == 511u) ? 1u : 0u;
    __syncthreads();
    if (lastflag) {
        double* red = (double*)xlds;  // reuse X-tile space
        const float c = atomicAdd(&counts[tid], 0.0f);  // coherence-point read
        const double p = (double)c / (double)NTOK;
        red[tid] = p * log(p + 1e-10);
        __syncthreads();
#pragma unroll
        for (int s = 256; s > 0; s >>= 1) {
            if (tid < s) red[tid] += red[tid + s];
            __syncthreads();
        }
        if (tid == 0) {
            const double sv = atomicAdd(sse_acc, 0.0);
            out[NELEM] = (float)((sv / (double)NELEM) * 1.25);
            out[NELEM + 1] = (float)exp(-red[0]);
        }
    }
}

extern "C" void kernel_launch(void* const* d_in, const int* in_sizes, int n_in,
                              void* d_out, int out_size, void* d_ws, size_t ws_size,
                              hipStream_t stream) {
    const float* in = (const float*)d_in[0];
    const float* w = (const float*)d_in[1];
    float* out = (float*)d_out;

    char* ws = (char*)d_ws;
    float* counts = (float*)(ws + 0);
    double* sse_acc = (double*)(ws + 2048);
    unsigned* ticket = (unsigned*)(ws + 2056);

    hipMemsetAsync(ws, 0, 2060, stream);  // counts + sse + ticket
    vq_main<<<512, 512, 0, stream>>>(in, w, out, counts, sse_acc, ticket);
}